// Round 2
// baseline (2832.268 us; speedup 1.0000x reference)
//
#include <hip/hip_runtime.h>
#include <stdint.h>

#define T_LEN 8192
#define DIN   1024
#define HD    1024
#define TH    3072
#define K_MAX 40

typedef __attribute__((ext_vector_type(8))) short bf16x8;
typedef __attribute__((ext_vector_type(4))) float f32x4;

__device__ __forceinline__ unsigned short f2bf(float x) {
    union { float f; unsigned u; } v; v.f = x;
    unsigned r = v.u + 0x7FFFu + ((v.u >> 16) & 1u);
    return (unsigned short)(r >> 16);
}

__device__ __forceinline__ bf16x8 pack8(float4 a, float4 b) {
    bf16x8 r;
    r[0] = (short)f2bf(a.x); r[1] = (short)f2bf(a.y);
    r[2] = (short)f2bf(a.z); r[3] = (short)f2bf(a.w);
    r[4] = (short)f2bf(b.x); r[5] = (short)f2bf(b.y);
    r[6] = (short)f2bf(b.z); r[7] = (short)f2bf(b.w);
    return r;
}

// async global->LDS, 16B per lane. LDS dest must be wave-uniform base + lane*16.
__device__ __forceinline__ void gld16(const void* g, void* l) {
    __builtin_amdgcn_global_load_lds(
        (const __attribute__((address_space(1))) unsigned int*)(uintptr_t)g,
        (__attribute__((address_space(3))) unsigned int*)(uintptr_t)l,
        16, 0, 0);
}

__device__ __forceinline__ float sigm(float x) { return 1.f / (1.f + __expf(-x)); }
__device__ __forceinline__ float tanh_fast(float x) { return 1.f - 2.f / (1.f + __expf(2.f * x)); }

// ---------------- transpose+cast Wi/Wh [K][3072] -> [3072][K] bf16 ----------------
__global__ void transpose_cast(const float* __restrict__ Wi, const float* __restrict__ Wh,
                               unsigned short* __restrict__ WiT, unsigned short* __restrict__ WhT) {
    const float* src = blockIdx.z ? Wh : Wi;
    unsigned short* dst = blockIdx.z ? WhT : WiT;
    int n0 = blockIdx.x * 64, k0 = blockIdx.y * 64;
    __shared__ unsigned short tile[64][65];
    int tid = threadIdx.x;
    for (int p = 0; p < 16; p++) {
        int idx = tid + p * 256;
        int kl = idx >> 6, nl = idx & 63;
        tile[kl][nl] = f2bf(src[(size_t)(k0 + kl) * TH + n0 + nl]);
    }
    __syncthreads();
    for (int p = 0; p < 16; p++) {
        int idx = tid + p * 256;
        int nl = idx >> 6, kl = idx & 63;
        dst[(size_t)(n0 + nl) * 1024 + k0 + kl] = tile[kl][nl];
    }
}

// ---------------- segment metadata (1 block, 1024 threads) ----------------
// meta[0..K_MAX): S_k counts ; meta[K_MAX..2K): offsets ; meta[2K]: last_state nonzero flag
__global__ void meta_kernel(const int* __restrict__ term, const float* __restrict__ last_state,
                            int* __restrict__ pos_list, int* __restrict__ meta) {
    __shared__ int part[1024];
    __shared__ int cnt[K_MAX];
    __shared__ int cur[K_MAX];
    __shared__ int flag;
    int tid = threadIdx.x;
    if (tid < K_MAX) cnt[tid] = 0;
    if (tid == 0) flag = 0;
    __syncthreads();
    int base = tid * 8;
    int mx = -1;
    for (int u = 0; u < 8; u++) {
        int t = base + u;
        int s = (t == 0 || term[t] != 0) ? t : -1;
        mx = s > mx ? s : mx;
    }
    part[tid] = mx;
    __syncthreads();
    for (int d = 1; d < 1024; d <<= 1) {
        int a = part[tid];
        int b = (tid >= d) ? part[tid - d] : -1;
        __syncthreads();
        part[tid] = a > b ? a : b;
        __syncthreads();
    }
    int run = (tid > 0) ? part[tid - 1] : -1;
    int kk[8];
    for (int u = 0; u < 8; u++) {
        int t = base + u;
        int s = (t == 0 || term[t] != 0) ? t : -1;
        run = s > run ? s : run;
        int ls = t - run;
        int k = ls < K_MAX ? ls : K_MAX - 1;
        kk[u] = k;
        atomicAdd(&cnt[k], 1);
    }
    if (last_state[tid] != 0.0f) atomicOr(&flag, 1);
    __syncthreads();
    if (tid == 0) {
        int off = 0;
        for (int k = 0; k < K_MAX; k++) {
            meta[k] = cnt[k];
            meta[K_MAX + k] = off;
            cur[k] = off;
            off += cnt[k];
        }
        meta[2 * K_MAX] = flag;
    }
    __syncthreads();
    for (int u = 0; u < 8; u++) {
        int idx = atomicAdd(&cur[kk[u]], 1);
        pos_list[idx] = base + u;
    }
}

// ---------------- gi = X @ Wi + bi  (128x128 bf16 MFMA, fp32->bf16 cast fused into A staging)
__global__ __launch_bounds__(256) void gemm_gi(const float* __restrict__ X,
                                               const unsigned short* __restrict__ WiT,
                                               const float* __restrict__ bi,
                                               float* __restrict__ gi) {
    __shared__ unsigned short As[128 * 32];   // 8 KB, row-major rows of 32 shorts (64 B)
    __shared__ unsigned short Bs[128 * 32];   // 8 KB
    int tid = threadIdx.x;
    int m0 = blockIdx.y * 128, n0 = blockIdx.x * 128;
    int lane = tid & 63, wave = tid >> 6;
    int wm = wave & 1, wn = wave >> 1;
    int quad = lane >> 4, l16 = lane & 15;
    // A staging mapping: chunk c in [0,512): row=c>>2, sub=c&3 (8 floats). Thread owns c=tid, tid+256.
    int arow0 = tid >> 2, sub = tid & 3;
    const float* xr0 = X + (size_t)(m0 + arow0) * 1024 + sub * 8;
    const float* xr1 = X + (size_t)(m0 + arow0 + 64) * 1024 + sub * 8;
    f32x4 acc[4][4] = {};
    for (int kb = 0; kb < 32; kb++) {
        int k0 = kb * 32;
        for (int p = 0; p < 2; p++) {      // B: 128 rows x 64 B = 512 chunks, gld16
            int c = tid + p * 256;
            int row = c >> 2, q = c & 3;
            gld16(WiT + (size_t)(n0 + row) * 1024 + k0 + q * 8, Bs + c * 8);
        }
        {   // A: load fp32, cast, lane-contiguous 16B stores (chunk id = tid, tid+256)
            float4 v0 = *(const float4*)(xr0 + k0);
            float4 v1 = *(const float4*)(xr0 + k0 + 4);
            float4 v2 = *(const float4*)(xr1 + k0);
            float4 v3 = *(const float4*)(xr1 + k0 + 4);
            *(bf16x8*)(As + tid * 8) = pack8(v0, v1);
            *(bf16x8*)(As + (tid + 256) * 8) = pack8(v2, v3);
        }
        __syncthreads();
        bf16x8 af[4], bfr[4];
        for (int i = 0; i < 4; i++)
            af[i] = *(const bf16x8*)(As + (wm * 64 + i * 16 + l16) * 32 + quad * 8);
        for (int j = 0; j < 4; j++)
            bfr[j] = *(const bf16x8*)(Bs + (wn * 64 + j * 16 + l16) * 32 + quad * 8);
        for (int i = 0; i < 4; i++)
            for (int j = 0; j < 4; j++)
                acc[i][j] = __builtin_amdgcn_mfma_f32_16x16x32_bf16(af[i], bfr[j], acc[i][j], 0, 0, 0);
        __syncthreads();
    }
    for (int j = 0; j < 4; j++) {
        int col = n0 + wn * 64 + j * 16 + l16;
        float bv = bi[col];
        for (int i = 0; i < 4; i++) {
            int rbase = m0 + wm * 64 + i * 16 + quad * 4;
            for (int r = 0; r < 4; r++)
                gi[(size_t)(rbase + r) * TH + col] = acc[i][j][r] + bv;
        }
    }
}

// ---------------- pass 0: segment starts, h_prev == 0 (or last_state for t==0) ----------------
__global__ void pass0_kernel(const float* __restrict__ gi, const float* __restrict__ bhn,
                             const float* __restrict__ last_state, const float* __restrict__ Wh,
                             const int* __restrict__ term, const int* __restrict__ pos_list,
                             const int* __restrict__ meta, float* __restrict__ out) {
    int S0 = meta[0];
    int b = blockIdx.x;
    if (b >= S0) return;
    int t = pos_list[meta[K_MAX] + b];
    int tid = threadIdx.x;
    bool ls_path = (t == 0) && (term[0] == 0) && (meta[2 * K_MAX] != 0);
    for (int u = 0; u < 4; u++) {
        int j = tid + u * 256;
        float gr = gi[(size_t)t * TH + j];
        float gz = gi[(size_t)t * TH + 1024 + j];
        float gn = gi[(size_t)t * TH + 2048 + j];
        float hp = 0.f, ghr = 0.f, ghz = 0.f, ghn = 0.f;
        if (ls_path) {  // general fallback (last_state != 0); not taken for this dataset
            hp = last_state[j];
            for (int k = 0; k < 1024; k++) {
                float hk = last_state[k];
                const float* w = Wh + (size_t)k * TH;
                ghr += hk * w[j]; ghz += hk * w[1024 + j]; ghn += hk * w[2048 + j];
            }
        }
        float r = sigm(gr + ghr);
        float z = sigm(gz + ghz);
        float n = tanh_fast(gn + r * (ghn + bhn[j]));
        float h = (1.f - z) * n + z * hp;
        out[(size_t)t * HD + j] = h;
        out[(size_t)(T_LEN + t) * HD + j] = h;
    }
}

// ---------------- pass k>=1: gathered-row GEMM h_prev @ Wh + fused gates ----------------
// Tile: 128 gathered rows x 64 h-cols x 3 gates, BK=32 (conflict-free LDS layout).
// 4 waves in 2(m) x 2(j): each wave 64 rows x 32 j-cols x 3 gates.
__global__ __launch_bounds__(256) void pass_gemm(const float* __restrict__ gi,
                                                 const float* __restrict__ bhn,
                                                 const unsigned short* __restrict__ WhT,
                                                 float* __restrict__ out,
                                                 const int* __restrict__ pos_list,
                                                 const int* __restrict__ meta, int k) {
    int S = meta[k];
    int r0 = blockIdx.y * 128;
    if (r0 >= S) return;
    int off = meta[K_MAX + k];
    int j0 = blockIdx.x * 64;
    __shared__ unsigned short As[128 * 32];   // 8 KB
    __shared__ unsigned short Bs[192 * 32];   // 12 KB (row: gate g*64 + jj)
    int tid = threadIdx.x;
    int lane = tid & 63, wave = tid >> 6;
    int wm = wave & 1, wn = wave >> 1;
    int quad = lane >> 4, l16 = lane & 15;

    // A gather: chunk c = tid (rows 0..63), tid+256 (rows 64..127); row=c>>2, sub=c&3.
    int arow0 = tid >> 2, sub = tid & 3;
    bool av0 = (r0 + arow0) < S;
    bool av1 = (r0 + arow0 + 64) < S;
    int t0 = av0 ? pos_list[off + r0 + arow0] : 1;
    int t1 = av1 ? pos_list[off + r0 + arow0 + 64] : 1;
    const float* h0 = out + (size_t)(t0 - 1) * HD + sub * 8;
    const float* h1 = out + (size_t)(t1 - 1) * HD + sub * 8;

    f32x4 acc[4][6] = {};
    for (int kb = 0; kb < 32; kb++) {
        int k0 = kb * 32;
        for (int p = 0; p < 3; p++) {      // B: 192 rows x 64 B = 768 chunks, gld16
            int c = tid + p * 256;
            int row = c >> 2, q = c & 3;
            int g = row >> 6, jj = row & 63;
            gld16(WhT + (size_t)(g * 1024 + j0 + jj) * 1024 + k0 + q * 8, Bs + c * 8);
        }
        {   // A: gather h_prev fp32, cast, lane-contiguous 16B stores
            float4 z4 = {0.f, 0.f, 0.f, 0.f};
            float4 v0 = av0 ? *(const float4*)(h0 + k0)     : z4;
            float4 v1 = av0 ? *(const float4*)(h0 + k0 + 4) : z4;
            float4 v2 = av1 ? *(const float4*)(h1 + k0)     : z4;
            float4 v3 = av1 ? *(const float4*)(h1 + k0 + 4) : z4;
            *(bf16x8*)(As + tid * 8) = pack8(v0, v1);
            *(bf16x8*)(As + (tid + 256) * 8) = pack8(v2, v3);
        }
        __syncthreads();
        bf16x8 af[4];
        for (int i = 0; i < 4; i++)
            af[i] = *(const bf16x8*)(As + (wm * 64 + i * 16 + l16) * 32 + quad * 8);
        for (int n = 0; n < 6; n++) {
            int g = n >> 1, h2 = n & 1;
            bf16x8 bv = *(const bf16x8*)(Bs + (g * 64 + wn * 32 + h2 * 16 + l16) * 32 + quad * 8);
            for (int i = 0; i < 4; i++)
                acc[i][n] = __builtin_amdgcn_mfma_f32_16x16x32_bf16(af[i], bv, acc[i][n], 0, 0, 0);
        }
        __syncthreads();
    }
    // epilogue: rows wm*64 + i*16 + quad*4 + r ; cols j0 + wn*32 + h2*16 + l16 ; gates via n=g*2+h2
    for (int i = 0; i < 4; i++) {
        for (int r = 0; r < 4; r++) {
            int rr = r0 + wm * 64 + i * 16 + quad * 4 + r;
            if (rr >= S) continue;
            int t = pos_list[off + rr];
            const float* girow = gi + (size_t)t * TH;
            const float* hprow = out + (size_t)(t - 1) * HD;
            float* o1 = out + (size_t)t * HD;
            float* o2 = out + (size_t)(T_LEN + t) * HD;
            for (int h2 = 0; h2 < 2; h2++) {
                int j = j0 + wn * 32 + h2 * 16 + l16;
                float ghr = acc[i][0 + h2][r];
                float ghz = acc[i][2 + h2][r];
                float ghn = acc[i][4 + h2][r];
                float rg = sigm(girow[j] + ghr);
                float zg = sigm(girow[1024 + j] + ghz);
                float ng = tanh_fast(girow[2048 + j] + rg * (ghn + bhn[j]));
                float h = (1.f - zg) * ng + zg * hprow[j];
                o1[j] = h;
                o2[j] = h;
            }
        }
    }
}

extern "C" void kernel_launch(void* const* d_in, const int* in_sizes, int n_in,
                              void* d_out, int out_size, void* d_ws, size_t ws_size,
                              hipStream_t stream) {
    const float* X          = (const float*)d_in[0];
    const int*   term       = (const int*)d_in[1];
    const float* last_state = (const float*)d_in[2];
    const float* Wi         = (const float*)d_in[3];
    const float* bi         = (const float*)d_in[4];
    const float* Wh         = (const float*)d_in[5];
    const float* bhn        = (const float*)d_in[6];
    float* out = (float*)d_out;

    char* ws = (char*)d_ws;
    float*          gi       = (float*)ws;                         // 100,663,296 B
    unsigned short* WiT      = (unsigned short*)(ws + 100663296);  //  6,291,456 B
    unsigned short* WhT      = (unsigned short*)(ws + 106954752);  //  6,291,456 B
    int*            pos_list = (int*)(ws + 113246208);             //     32,768 B
    int*            meta     = (int*)(ws + 113278976);             //        512 B

    transpose_cast<<<dim3(48, 16, 2), dim3(256), 0, stream>>>(Wi, Wh, WiT, WhT);
    meta_kernel<<<dim3(1), dim3(1024), 0, stream>>>(term, last_state, pos_list, meta);
    gemm_gi<<<dim3(24, 64), dim3(256), 0, stream>>>(X, WiT, bi, gi);
    pass0_kernel<<<dim3(8192), dim3(256), 0, stream>>>(gi, bhn, last_state, Wh, term, pos_list, meta, out);
    for (int k = 1; k < K_MAX; k++) {
        int rows_max = T_LEN / (k + 1);     // S_k <= T/(k+1)
        int gy = (rows_max + 127) / 128;
        pass_gemm<<<dim3(16, gy), dim3(256), 0, stream>>>(gi, bhn, WhT, out, pos_list, meta, k);
    }
}

// Round 3
// 808.575 us; speedup vs baseline: 3.5028x; 3.5028x over previous
//
#include <hip/hip_runtime.h>
#include <stdint.h>

#define T_LEN 8192
#define DIN   1024
#define HD    1024
#define TH    3072
#define K_MAX 40

typedef __attribute__((ext_vector_type(8))) short bf16x8;
typedef __attribute__((ext_vector_type(4))) float f32x4;

__device__ __forceinline__ unsigned short f2bf(float x) {
    union { float f; unsigned u; } v; v.f = x;
    unsigned r = v.u + 0x7FFFu + ((v.u >> 16) & 1u);
    return (unsigned short)(r >> 16);
}

__device__ __forceinline__ bf16x8 pack8(float4 a, float4 b) {
    bf16x8 r;
    r[0] = (short)f2bf(a.x); r[1] = (short)f2bf(a.y);
    r[2] = (short)f2bf(a.z); r[3] = (short)f2bf(a.w);
    r[4] = (short)f2bf(b.x); r[5] = (short)f2bf(b.y);
    r[6] = (short)f2bf(b.z); r[7] = (short)f2bf(b.w);
    return r;
}

// async global->LDS, 16B per lane. LDS dest must be wave-uniform base + lane*16.
__device__ __forceinline__ void gld16(const void* g, void* l) {
    __builtin_amdgcn_global_load_lds(
        (const __attribute__((address_space(1))) unsigned int*)(uintptr_t)g,
        (__attribute__((address_space(3))) unsigned int*)(uintptr_t)l,
        16, 0, 0);
}

__device__ __forceinline__ float sigm(float x) { return 1.f / (1.f + __expf(-x)); }
__device__ __forceinline__ float tanh_fast(float x) { return 1.f - 2.f / (1.f + __expf(2.f * x)); }

// ---------------- transpose+cast Wi/Wh [K][3072] -> [3072][K] bf16 ----------------
__global__ void transpose_cast(const float* __restrict__ Wi, const float* __restrict__ Wh,
                               unsigned short* __restrict__ WiT, unsigned short* __restrict__ WhT) {
    const float* src = blockIdx.z ? Wh : Wi;
    unsigned short* dst = blockIdx.z ? WhT : WiT;
    int n0 = blockIdx.x * 64, k0 = blockIdx.y * 64;
    __shared__ unsigned short tile[64][65];
    int tid = threadIdx.x;
    for (int p = 0; p < 16; p++) {
        int idx = tid + p * 256;
        int kl = idx >> 6, nl = idx & 63;
        tile[kl][nl] = f2bf(src[(size_t)(k0 + kl) * TH + n0 + nl]);
    }
    __syncthreads();
    for (int p = 0; p < 16; p++) {
        int idx = tid + p * 256;
        int nl = idx >> 6, kl = idx & 63;
        dst[(size_t)(n0 + nl) * 1024 + k0 + kl] = tile[kl][nl];
    }
}

// ---------------- segment metadata (1 block, 1024 threads) ----------------
// meta[0..K_MAX): S_k counts ; meta[K_MAX..2K): offsets ; meta[2K]: last_state nonzero flag
__global__ void meta_kernel(const int* __restrict__ term, const float* __restrict__ last_state,
                            int* __restrict__ pos_list, int* __restrict__ meta) {
    __shared__ int part[1024];
    __shared__ int cnt[K_MAX];
    __shared__ int cur[K_MAX];
    __shared__ int flag;
    int tid = threadIdx.x;
    if (tid < K_MAX) cnt[tid] = 0;
    if (tid == 0) flag = 0;
    __syncthreads();
    int base = tid * 8;
    int mx = -1;
    for (int u = 0; u < 8; u++) {
        int t = base + u;
        int s = (t == 0 || term[t] != 0) ? t : -1;
        mx = s > mx ? s : mx;
    }
    part[tid] = mx;
    __syncthreads();
    for (int d = 1; d < 1024; d <<= 1) {
        int a = part[tid];
        int b = (tid >= d) ? part[tid - d] : -1;
        __syncthreads();
        part[tid] = a > b ? a : b;
        __syncthreads();
    }
    int run = (tid > 0) ? part[tid - 1] : -1;
    int kk[8];
    for (int u = 0; u < 8; u++) {
        int t = base + u;
        int s = (t == 0 || term[t] != 0) ? t : -1;
        run = s > run ? s : run;
        int ls = t - run;
        int k = ls < K_MAX ? ls : K_MAX - 1;
        kk[u] = k;
        atomicAdd(&cnt[k], 1);
    }
    if (last_state[tid] != 0.0f) atomicOr(&flag, 1);
    __syncthreads();
    if (tid == 0) {
        int off = 0;
        for (int k = 0; k < K_MAX; k++) {
            meta[k] = cnt[k];
            meta[K_MAX + k] = off;
            cur[k] = off;
            off += cnt[k];
        }
        meta[2 * K_MAX] = flag;
    }
    __syncthreads();
    for (int u = 0; u < 8; u++) {
        int idx = atomicAdd(&cur[kk[u]], 1);
        pos_list[idx] = base + u;
    }
}

// ---------------- gi = X @ Wi + bi  (128x128 bf16 MFMA, fp32->bf16 cast fused into A staging)
__global__ __launch_bounds__(256) void gemm_gi(const float* __restrict__ X,
                                               const unsigned short* __restrict__ WiT,
                                               const float* __restrict__ bi,
                                               float* __restrict__ gi) {
    __shared__ unsigned short As[128 * 32];   // 8 KB, row-major rows of 32 shorts (64 B)
    __shared__ unsigned short Bs[128 * 32];   // 8 KB
    int tid = threadIdx.x;
    int m0 = blockIdx.y * 128, n0 = blockIdx.x * 128;
    int lane = tid & 63, wave = tid >> 6;
    int wm = wave & 1, wn = wave >> 1;
    int quad = lane >> 4, l16 = lane & 15;
    // A staging mapping: chunk c in [0,512): row=c>>2, sub=c&3 (8 floats). Thread owns c=tid, tid+256.
    int arow0 = tid >> 2, sub = tid & 3;
    const float* xr0 = X + (size_t)(m0 + arow0) * 1024 + sub * 8;
    const float* xr1 = X + (size_t)(m0 + arow0 + 64) * 1024 + sub * 8;
    f32x4 acc[4][4] = {};   // 16 f32x4 = promotion-safe ceiling; do NOT enlarge (r2: 24 -> scratch spill)
    for (int kb = 0; kb < 32; kb++) {
        int k0 = kb * 32;
        for (int p = 0; p < 2; p++) {      // B: 128 rows x 64 B = 512 chunks, gld16
            int c = tid + p * 256;
            int row = c >> 2, q = c & 3;
            gld16(WiT + (size_t)(n0 + row) * 1024 + k0 + q * 8, Bs + c * 8);
        }
        {   // A: load fp32, cast, lane-contiguous 16B stores (chunk id = tid, tid+256)
            float4 v0 = *(const float4*)(xr0 + k0);
            float4 v1 = *(const float4*)(xr0 + k0 + 4);
            float4 v2 = *(const float4*)(xr1 + k0);
            float4 v3 = *(const float4*)(xr1 + k0 + 4);
            *(bf16x8*)(As + tid * 8) = pack8(v0, v1);
            *(bf16x8*)(As + (tid + 256) * 8) = pack8(v2, v3);
        }
        __syncthreads();
        bf16x8 af[4], bfr[4];
        for (int i = 0; i < 4; i++)
            af[i] = *(const bf16x8*)(As + (wm * 64 + i * 16 + l16) * 32 + quad * 8);
        for (int j = 0; j < 4; j++)
            bfr[j] = *(const bf16x8*)(Bs + (wn * 64 + j * 16 + l16) * 32 + quad * 8);
        for (int i = 0; i < 4; i++)
            for (int j = 0; j < 4; j++)
                acc[i][j] = __builtin_amdgcn_mfma_f32_16x16x32_bf16(af[i], bfr[j], acc[i][j], 0, 0, 0);
        __syncthreads();
    }
    for (int j = 0; j < 4; j++) {
        int col = n0 + wn * 64 + j * 16 + l16;
        float bv = bi[col];
        for (int i = 0; i < 4; i++) {
            int rbase = m0 + wm * 64 + i * 16 + quad * 4;
            for (int r = 0; r < 4; r++)
                gi[(size_t)(rbase + r) * TH + col] = acc[i][j][r] + bv;
        }
    }
}

// ---------------- pass 0: segment starts, h_prev == 0 (or last_state for t==0) ----------------
__global__ void pass0_kernel(const float* __restrict__ gi, const float* __restrict__ bhn,
                             const float* __restrict__ last_state, const float* __restrict__ Wh,
                             const int* __restrict__ term, const int* __restrict__ pos_list,
                             const int* __restrict__ meta, float* __restrict__ out) {
    int S0 = meta[0];
    int b = blockIdx.x;
    if (b >= S0) return;
    int t = pos_list[meta[K_MAX] + b];
    int tid = threadIdx.x;
    bool ls_path = (t == 0) && (term[0] == 0) && (meta[2 * K_MAX] != 0);
    for (int u = 0; u < 4; u++) {
        int j = tid + u * 256;
        float gr = gi[(size_t)t * TH + j];
        float gz = gi[(size_t)t * TH + 1024 + j];
        float gn = gi[(size_t)t * TH + 2048 + j];
        float hp = 0.f, ghr = 0.f, ghz = 0.f, ghn = 0.f;
        if (ls_path) {  // general fallback (last_state != 0); not taken for this dataset
            hp = last_state[j];
            for (int k = 0; k < 1024; k++) {
                float hk = last_state[k];
                const float* w = Wh + (size_t)k * TH;
                ghr += hk * w[j]; ghz += hk * w[1024 + j]; ghn += hk * w[2048 + j];
            }
        }
        float r = sigm(gr + ghr);
        float z = sigm(gz + ghz);
        float n = tanh_fast(gn + r * (ghn + bhn[j]));
        float h = (1.f - z) * n + z * hp;
        out[(size_t)t * HD + j] = h;
        out[(size_t)(T_LEN + t) * HD + j] = h;
    }
}

// ---------------- pass k>=1: gathered-row GEMM h_prev @ Wh + fused gates ----------------
// Tile: 64 gathered rows x 64 h-cols x 3 gates, BK=32 (conflict-free 64B-row LDS layout).
// 4 waves in 2(row)x2(col): each wave 32 rows x 32 j-cols x 3 gates.
// REGISTER BUDGET: af[2] + acc[2][6] = 14 f32x4-equivalents per thread. Round 2's
// acc[4][6] (24 vectors) exceeded the aggregate-promotion threshold and spilled the
// whole accumulator array to scratch (VGPR_Count=28, 819 MB scratch writes/dispatch).
// Keep accumulator aggregates <= 16 vectors.
__global__ __launch_bounds__(256) void pass_gemm(const float* __restrict__ gi,
                                                 const float* __restrict__ bhn,
                                                 const unsigned short* __restrict__ WhT,
                                                 float* __restrict__ out,
                                                 const int* __restrict__ pos_list,
                                                 const int* __restrict__ meta, int k) {
    int S = meta[k];
    int r0 = blockIdx.y * 64;
    if (r0 >= S) return;
    int off = meta[K_MAX + k];
    int j0 = blockIdx.x * 64;
    __shared__ unsigned short As[64 * 32];    // 4 KB
    __shared__ unsigned short Bs[192 * 32];   // 12 KB (row: gate g*64 + jj)
    int tid = threadIdx.x;
    int lane = tid & 63, wave = tid >> 6;
    int wm = wave & 1, wn = wave >> 1;
    int quad = lane >> 4, l16 = lane & 15;

    // A gather: 256 chunks (64 rows x 4 sub); chunk id = tid; row=tid>>2, sub=tid&3.
    int arow = tid >> 2, sub = tid & 3;
    bool av = (r0 + arow) < S;
    int t_a = av ? pos_list[off + r0 + arow] : 1;
    const float* hsrc = out + (size_t)(t_a - 1) * HD + sub * 8;

    f32x4 acc[2][6] = {};   // 12 vectors — promotion-safe
    for (int kb = 0; kb < 32; kb++) {
        int k0 = kb * 32;
        for (int p = 0; p < 3; p++) {      // B: 192 rows x 64 B = 768 chunks, gld16
            int c = tid + p * 256;
            int row = c >> 2, q = c & 3;
            int g = row >> 6, jj = row & 63;
            gld16(WhT + (size_t)(g * 1024 + j0 + jj) * 1024 + k0 + q * 8, Bs + c * 8);
        }
        {   // A: gather h_prev fp32, cast, lane-contiguous 16B store
            float4 z4 = {0.f, 0.f, 0.f, 0.f};
            float4 v0 = av ? *(const float4*)(hsrc + k0)     : z4;
            float4 v1 = av ? *(const float4*)(hsrc + k0 + 4) : z4;
            *(bf16x8*)(As + tid * 8) = pack8(v0, v1);
        }
        __syncthreads();
        bf16x8 af[2];
        for (int i = 0; i < 2; i++)
            af[i] = *(const bf16x8*)(As + (wm * 32 + i * 16 + l16) * 32 + quad * 8);
        for (int n = 0; n < 6; n++) {
            int g = n >> 1, jh = n & 1;
            bf16x8 bv = *(const bf16x8*)(Bs + (g * 64 + wn * 32 + jh * 16 + l16) * 32 + quad * 8);
            for (int i = 0; i < 2; i++)
                acc[i][n] = __builtin_amdgcn_mfma_f32_16x16x32_bf16(af[i], bv, acc[i][n], 0, 0, 0);
        }
        __syncthreads();
    }
    // epilogue: rows r0 + wm*32 + i*16 + quad*4 + r ; cols j0 + wn*32 + jh*16 + l16 ; n = g*2+jh
    for (int i = 0; i < 2; i++) {
        for (int r = 0; r < 4; r++) {
            int rr = r0 + wm * 32 + i * 16 + quad * 4 + r;
            if (rr >= S) continue;
            int t = pos_list[off + rr];
            const float* girow = gi + (size_t)t * TH;
            const float* hprow = out + (size_t)(t - 1) * HD;
            float* o1 = out + (size_t)t * HD;
            float* o2 = out + (size_t)(T_LEN + t) * HD;
            for (int jh = 0; jh < 2; jh++) {
                int j = j0 + wn * 32 + jh * 16 + l16;
                float ghr = acc[i][0 + jh][r];
                float ghz = acc[i][2 + jh][r];
                float ghn = acc[i][4 + jh][r];
                float rg = sigm(girow[j] + ghr);
                float zg = sigm(girow[1024 + j] + ghz);
                float ng = tanh_fast(girow[2048 + j] + rg * (ghn + bhn[j]));
                float h = (1.f - zg) * ng + zg * hprow[j];
                o1[j] = h;
                o2[j] = h;
            }
        }
    }
}

extern "C" void kernel_launch(void* const* d_in, const int* in_sizes, int n_in,
                              void* d_out, int out_size, void* d_ws, size_t ws_size,
                              hipStream_t stream) {
    const float* X          = (const float*)d_in[0];
    const int*   term       = (const int*)d_in[1];
    const float* last_state = (const float*)d_in[2];
    const float* Wi         = (const float*)d_in[3];
    const float* bi         = (const float*)d_in[4];
    const float* Wh         = (const float*)d_in[5];
    const float* bhn        = (const float*)d_in[6];
    float* out = (float*)d_out;

    char* ws = (char*)d_ws;
    float*          gi       = (float*)ws;                         // 100,663,296 B
    unsigned short* WiT      = (unsigned short*)(ws + 100663296);  //  6,291,456 B
    unsigned short* WhT      = (unsigned short*)(ws + 106954752);  //  6,291,456 B
    int*            pos_list = (int*)(ws + 113246208);             //     32,768 B
    int*            meta     = (int*)(ws + 113278976);             //        512 B

    transpose_cast<<<dim3(48, 16, 2), dim3(256), 0, stream>>>(Wi, Wh, WiT, WhT);
    meta_kernel<<<dim3(1), dim3(1024), 0, stream>>>(term, last_state, pos_list, meta);
    gemm_gi<<<dim3(24, 64), dim3(256), 0, stream>>>(X, WiT, bi, gi);
    pass0_kernel<<<dim3(8192), dim3(256), 0, stream>>>(gi, bhn, last_state, Wh, term, pos_list, meta, out);
    for (int k = 1; k < K_MAX; k++) {
        int rows_max = T_LEN / (k + 1);     // S_k <= T/(k+1)
        int gy = (rows_max + 63) / 64;
        pass_gemm<<<dim3(16, gy), dim3(256), 0, stream>>>(gi, bhn, WhT, out, pos_list, meta, k);
    }
}

// Round 4
// 446.936 us; speedup vs baseline: 6.3371x; 1.8092x over previous
//
#include <hip/hip_runtime.h>
#include <stdint.h>

#define T_LEN 8192
#define DIN   1024
#define HD    1024
#define TH    3072
#define NB    16      // buckets: 0..14 exact local_step, 15 = clamp (handled by tail_kernel)

typedef __attribute__((ext_vector_type(8))) short bf16x8;
typedef __attribute__((ext_vector_type(4))) float f32x4;

__device__ __forceinline__ unsigned short f2bf(float x) {
    union { float f; unsigned u; } v; v.f = x;
    unsigned r = v.u + 0x7FFFu + ((v.u >> 16) & 1u);
    return (unsigned short)(r >> 16);
}

// async global->LDS, 16B per lane. LDS dest must be wave-uniform base + lane*16;
// global address may be per-lane arbitrary (gather OK).
__device__ __forceinline__ void gld16(const void* g, void* l) {
    __builtin_amdgcn_global_load_lds(
        (const __attribute__((address_space(1))) unsigned int*)(uintptr_t)g,
        (__attribute__((address_space(3))) unsigned int*)(uintptr_t)l,
        16, 0, 0);
}

__device__ __forceinline__ float sigm(float x) { return 1.f / (1.f + __expf(-x)); }
__device__ __forceinline__ float tanh_fast(float x) { return 1.f - 2.f / (1.f + __expf(2.f * x)); }

// ---------------- cast X -> bf16 (r3 lesson: keep casts OFF the GEMM critical path) ----
__global__ void cast_x(const float* __restrict__ X, unsigned short* __restrict__ Xb) {
    int idx = (blockIdx.x * 256 + threadIdx.x) * 4;
    float4 v = *(const float4*)(X + idx);
    ushort4 o; o.x = f2bf(v.x); o.y = f2bf(v.y); o.z = f2bf(v.z); o.w = f2bf(v.w);
    *(ushort4*)(Xb + idx) = o;
}

// ---------------- transpose+cast Wi/Wh [K][3072] -> [3072][K] bf16 ----------------
__global__ void transpose_cast(const float* __restrict__ Wi, const float* __restrict__ Wh,
                               unsigned short* __restrict__ WiT, unsigned short* __restrict__ WhT) {
    const float* src = blockIdx.z ? Wh : Wi;
    unsigned short* dst = blockIdx.z ? WhT : WiT;
    int n0 = blockIdx.x * 64, k0 = blockIdx.y * 64;
    __shared__ unsigned short tile[64][65];
    int tid = threadIdx.x;
    for (int p = 0; p < 16; p++) {
        int idx = tid + p * 256;
        int kl = idx >> 6, nl = idx & 63;
        tile[kl][nl] = f2bf(src[(size_t)(k0 + kl) * TH + n0 + nl]);
    }
    __syncthreads();
    for (int p = 0; p < 16; p++) {
        int idx = tid + p * 256;
        int nl = idx >> 6, kl = idx & 63;
        dst[(size_t)(n0 + nl) * 1024 + k0 + kl] = tile[kl][nl];
    }
}

// ---------------- segment metadata (1 block, 1024 threads) ----------------
// meta[0..NB): counts ; meta[NB..2NB): offsets ; meta[2NB]: last_state nonzero flag
__global__ void meta_kernel(const int* __restrict__ term, const float* __restrict__ last_state,
                            int* __restrict__ pos_list, int* __restrict__ meta) {
    __shared__ int part[1024];
    __shared__ int cnt[NB];
    __shared__ int cur[NB];
    __shared__ int flag;
    int tid = threadIdx.x;
    if (tid < NB) cnt[tid] = 0;
    if (tid == 0) flag = 0;
    __syncthreads();
    int base = tid * 8;
    int mx = -1;
    for (int u = 0; u < 8; u++) {
        int t = base + u;
        int s = (t == 0 || term[t] != 0) ? t : -1;
        mx = s > mx ? s : mx;
    }
    part[tid] = mx;
    __syncthreads();
    for (int d = 1; d < 1024; d <<= 1) {
        int a = part[tid];
        int b = (tid >= d) ? part[tid - d] : -1;
        __syncthreads();
        part[tid] = a > b ? a : b;
        __syncthreads();
    }
    int run = (tid > 0) ? part[tid - 1] : -1;
    int kk[8];
    for (int u = 0; u < 8; u++) {
        int t = base + u;
        int s = (t == 0 || term[t] != 0) ? t : -1;
        run = s > run ? s : run;
        int ls = t - run;
        int k = ls < NB ? ls : NB - 1;
        kk[u] = k;
        atomicAdd(&cnt[k], 1);
    }
    if (last_state[tid] != 0.0f) atomicOr(&flag, 1);
    __syncthreads();
    if (tid == 0) {
        int off = 0;
        for (int k = 0; k < NB; k++) {
            meta[k] = cnt[k];
            meta[NB + k] = off;
            cur[k] = off;
            off += cnt[k];
        }
        meta[2 * NB] = flag;
    }
    __syncthreads();
    for (int u = 0; u < 8; u++) {
        int idx = atomicAdd(&cur[kk[u]], 1);
        pos_list[idx] = base + u;
    }
}

// ---------------- gi = Xb @ WiT^T + bi  (round-1 form: 77.6 us, MfmaUtil 27%) ----------
__global__ __launch_bounds__(256) void gemm_gi(const unsigned short* __restrict__ Xb,
                                               const unsigned short* __restrict__ WiT,
                                               const float* __restrict__ bi,
                                               float* __restrict__ gi) {
    __shared__ unsigned short As[128 * 32];
    __shared__ unsigned short Bs[128 * 32];
    int tid = threadIdx.x;
    int m0 = blockIdx.y * 128, n0 = blockIdx.x * 128;
    int lane = tid & 63, wave = tid >> 6;
    int wm = wave & 1, wn = wave >> 1;
    int quad = lane >> 4, l16 = lane & 15;
    f32x4 acc[4][4] = {};   // 16 f32x4 = promotion ceiling; do NOT enlarge (r2: 24 -> scratch spill)
    for (int kb = 0; kb < 32; kb++) {
        int k0 = kb * 32;
        for (int p = 0; p < 2; p++) {
            int c = tid + p * 256;
            int row = c >> 2, cb = c & 3;
            gld16(Xb + (size_t)(m0 + row) * 1024 + k0 + cb * 8, As + c * 8);
            gld16(WiT + (size_t)(n0 + row) * 1024 + k0 + cb * 8, Bs + c * 8);
        }
        __syncthreads();
        bf16x8 af[4], bfr[4];
        for (int i = 0; i < 4; i++)
            af[i] = *(const bf16x8*)(As + (wm * 64 + i * 16 + l16) * 32 + quad * 8);
        for (int j = 0; j < 4; j++)
            bfr[j] = *(const bf16x8*)(Bs + (wn * 64 + j * 16 + l16) * 32 + quad * 8);
        for (int i = 0; i < 4; i++)
            for (int j = 0; j < 4; j++)
                acc[i][j] = __builtin_amdgcn_mfma_f32_16x16x32_bf16(af[i], bfr[j], acc[i][j], 0, 0, 0);
        __syncthreads();
    }
    for (int j = 0; j < 4; j++) {
        int col = n0 + wn * 64 + j * 16 + l16;
        float bv = bi[col];
        for (int i = 0; i < 4; i++) {
            int rbase = m0 + wm * 64 + i * 16 + quad * 4;
            for (int r = 0; r < 4; r++)
                gi[(size_t)(rbase + r) * TH + col] = acc[i][j][r] + bv;
        }
    }
}

// ---------------- pass 0: segment starts, h_prev == 0 (or last_state for t==0) ----------
__global__ void pass0_kernel(const float* __restrict__ gi, const float* __restrict__ bhn,
                             const float* __restrict__ last_state, const float* __restrict__ Wh,
                             const int* __restrict__ term, const int* __restrict__ pos_list,
                             const int* __restrict__ meta, float* __restrict__ out,
                             unsigned short* __restrict__ hb) {
    int S0 = meta[0];
    int b = blockIdx.x;
    if (b >= S0) return;
    int t = pos_list[meta[NB] + b];
    int tid = threadIdx.x;
    bool ls_path = (t == 0) && (term[0] == 0) && (meta[2 * NB] != 0);
    for (int u = 0; u < 4; u++) {
        int j = tid + u * 256;
        float gr = gi[(size_t)t * TH + j];
        float gz = gi[(size_t)t * TH + 1024 + j];
        float gn = gi[(size_t)t * TH + 2048 + j];
        float hp = 0.f, ghr = 0.f, ghz = 0.f, ghn = 0.f;
        if (ls_path) {  // general fallback (last_state != 0); not taken for this dataset
            hp = last_state[j];
            for (int k = 0; k < 1024; k++) {
                float hk = last_state[k];
                const float* w = Wh + (size_t)k * TH;
                ghr += hk * w[j]; ghz += hk * w[1024 + j]; ghn += hk * w[2048 + j];
            }
        }
        float r = sigm(gr + ghr);
        float z = sigm(gz + ghz);
        float n = tanh_fast(gn + r * (ghn + bhn[j]));
        float h = (1.f - z) * n + z * hp;
        out[(size_t)t * HD + j] = h;
        out[(size_t)(T_LEN + t) * HD + j] = h;
        hb[(size_t)t * HD + j] = f2bf(h);
    }
}

// ---------------- pass k in [1,14]: gathered-row GEMM h_prev @ Wh + fused gates --------
// Tile: 64 gathered rows x 64 h-cols x 3 gates. BK=64 per outer iteration, staged as
// TWO 32-K sub-tiles (each 64 B-row conflict-free layout) -> 16 iterations, half the
// barriers of r3. ALL staging async gld16 (A gathered from bf16 hb).
// Register budget: acc[2][6]=12 f32x4 — promotion-safe (r2: >16 vectors spills).
__global__ __launch_bounds__(256) void pass_gemm(const float* __restrict__ gi,
                                                 const float* __restrict__ bhn,
                                                 const unsigned short* __restrict__ WhT,
                                                 const unsigned short* __restrict__ hb,
                                                 float* __restrict__ out,
                                                 unsigned short* __restrict__ hbw,
                                                 const int* __restrict__ pos_list,
                                                 const int* __restrict__ meta, int k) {
    int S = meta[k];
    int r0 = blockIdx.y * 64;
    if (r0 >= S) return;
    int off = meta[NB + k];
    int j0 = blockIdx.x * 64;
    __shared__ unsigned short As[2 * 64 * 32];    //  8 KB (two 32-K sub-tiles)
    __shared__ unsigned short Bs[2 * 192 * 32];   // 24 KB (row: gate g*64 + jj)
    int tid = threadIdx.x;
    int lane = tid & 63, wave = tid >> 6;
    int wm = wave & 1, wn = wave >> 1;
    int quad = lane >> 4, l16 = lane & 15;

    // A gather: 256 chunks per sub-tile; chunk id = tid; row=tid>>2, sub=tid&3.
    int arow = tid >> 2, sub = tid & 3;
    bool av = (r0 + arow) < S;
    int t_a = av ? pos_list[off + r0 + arow] : 1;
    const unsigned short* hsrc = hb + (size_t)(t_a - 1) * HD + sub * 8;

    f32x4 acc[2][6] = {};
    for (int kb = 0; kb < 16; kb++) {
        int k0 = kb * 64;
        for (int ks = 0; ks < 2; ks++) {
            int kk0 = k0 + ks * 32;
            for (int p = 0; p < 3; p++) {      // B sub-tile: 768 chunks
                int c = tid + p * 256;
                int row = c >> 2, q = c & 3;
                int g = row >> 6, jj = row & 63;
                gld16(WhT + (size_t)(g * 1024 + j0 + jj) * 1024 + kk0 + q * 8,
                      Bs + ks * 6144 + c * 8);
            }
            // A sub-tile: 256 chunks (gathered rows; garbage rows >= S harmless)
            gld16(hsrc + kk0, As + ks * 2048 + tid * 8);
        }
        __syncthreads();
        for (int ks = 0; ks < 2; ks++) {
            bf16x8 af[2];
            for (int i = 0; i < 2; i++)
                af[i] = *(const bf16x8*)(As + ks * 2048 + (wm * 32 + i * 16 + l16) * 32 + quad * 8);
            for (int n = 0; n < 6; n++) {
                int g = n >> 1, jh = n & 1;
                bf16x8 bv = *(const bf16x8*)(Bs + ks * 6144 + (g * 64 + wn * 32 + jh * 16 + l16) * 32 + quad * 8);
                for (int i = 0; i < 2; i++)
                    acc[i][n] = __builtin_amdgcn_mfma_f32_16x16x32_bf16(af[i], bv, acc[i][n], 0, 0, 0);
            }
        }
        __syncthreads();
    }
    // epilogue: rows r0 + wm*32 + i*16 + quad*4 + r ; cols j0 + wn*32 + jh*16 + l16
    for (int i = 0; i < 2; i++) {
        for (int r = 0; r < 4; r++) {
            int rr = r0 + wm * 32 + i * 16 + quad * 4 + r;
            if (rr >= S) continue;
            int t = pos_list[off + rr];
            const float* girow = gi + (size_t)t * TH;
            const float* hprow = out + (size_t)(t - 1) * HD;
            float* o1 = out + (size_t)t * HD;
            float* o2 = out + (size_t)(T_LEN + t) * HD;
            unsigned short* hbrow = hbw + (size_t)t * HD;
            for (int jh = 0; jh < 2; jh++) {
                int j = j0 + wn * 32 + jh * 16 + l16;
                float ghr = acc[i][0 + jh][r];
                float ghz = acc[i][2 + jh][r];
                float ghn = acc[i][4 + jh][r];
                float rg = sigm(girow[j] + ghr);
                float zg = sigm(girow[1024 + j] + ghz);
                float ng = tanh_fast(girow[2048 + j] + rg * (ghn + bhn[j]));
                float h = (1.f - zg) * ng + zg * hprow[j];
                o1[j] = h;
                o2[j] = h;
                hbrow[j] = f2bf(h);
            }
        }
    }
}

// ---------------- tail: positions with local_step >= NB-1, sequential per time order ----
// Expected S==0 for Bernoulli(1/2) terminations (P ~ 6%); correctness path for any input.
__global__ void tail_kernel(const float* __restrict__ gi, const float* __restrict__ bhn,
                            const float* __restrict__ Wh,
                            const int* __restrict__ pos_list, const int* __restrict__ meta,
                            float* __restrict__ out) {
    __shared__ int pos[T_LEN];
    int S = meta[NB - 1];
    if (S == 0) return;
    int off = meta[NB + NB - 1];
    int tid = threadIdx.x;
    for (int i = tid; i < S; i += 256) pos[i] = pos_list[off + i];
    __syncthreads();
    if (tid == 0) {   // insertion sort by t (S expected tiny)
        for (int i = 1; i < S; i++) {
            int v = pos[i], j = i - 1;
            while (j >= 0 && pos[j] > v) { pos[j + 1] = pos[j]; j--; }
            pos[j + 1] = v;
        }
    }
    __syncthreads();
    for (int s = 0; s < S; s++) {
        int t = pos[s];
        const float* hp = out + (size_t)(t - 1) * HD;
        const float* girow = gi + (size_t)t * TH;
        // each thread: 4 h-cols, 3 dots each
        float hv[4];
        for (int c = 0; c < 4; c++) {
            int j = tid * 4 + c;
            float ghr = 0.f, ghz = 0.f, ghn = 0.f;
            for (int kk = 0; kk < 1024; kk++) {
                float hk = hp[kk];
                const float* w = Wh + (size_t)kk * TH;
                ghr += hk * w[j]; ghz += hk * w[1024 + j]; ghn += hk * w[2048 + j];
            }
            float rg = sigm(girow[j] + ghr);
            float zg = sigm(girow[1024 + j] + ghz);
            float ng = tanh_fast(girow[2048 + j] + rg * (ghn + bhn[j]));
            hv[c] = (1.f - zg) * ng + zg * hp[j];
        }
        __syncthreads();   // all reads of h_{t-1} complete before writing h_t
        for (int c = 0; c < 4; c++) {
            int j = tid * 4 + c;
            out[(size_t)t * HD + j] = hv[c];
            out[(size_t)(T_LEN + t) * HD + j] = hv[c];
        }
        __syncthreads();
    }
}

extern "C" void kernel_launch(void* const* d_in, const int* in_sizes, int n_in,
                              void* d_out, int out_size, void* d_ws, size_t ws_size,
                              hipStream_t stream) {
    const float* X          = (const float*)d_in[0];
    const int*   term       = (const int*)d_in[1];
    const float* last_state = (const float*)d_in[2];
    const float* Wi         = (const float*)d_in[3];
    const float* bi         = (const float*)d_in[4];
    const float* Wh         = (const float*)d_in[5];
    const float* bhn        = (const float*)d_in[6];
    float* out = (float*)d_out;

    char* ws = (char*)d_ws;
    float*          gi       = (float*)ws;                         // 100,663,296 B
    unsigned short* Xb       = (unsigned short*)(ws + 100663296);  // 16,777,216 B (reused as hb)
    unsigned short* hb       = Xb;  // Xb dead after gemm_gi; stream order guarantees safety
    unsigned short* WiT      = (unsigned short*)(ws + 117440512);  //  6,291,456 B
    unsigned short* WhT      = (unsigned short*)(ws + 123731968);  //  6,291,456 B
    int*            pos_list = (int*)(ws + 130023424);             //     32,768 B
    int*            meta     = (int*)(ws + 130056192);             //        512 B

    cast_x<<<dim3(8192), dim3(256), 0, stream>>>(X, Xb);
    transpose_cast<<<dim3(48, 16, 2), dim3(256), 0, stream>>>(Wi, Wh, WiT, WhT);
    meta_kernel<<<dim3(1), dim3(1024), 0, stream>>>(term, last_state, pos_list, meta);
    gemm_gi<<<dim3(24, 64), dim3(256), 0, stream>>>(Xb, WiT, bi, gi);
    pass0_kernel<<<dim3(8192), dim3(256), 0, stream>>>(gi, bhn, last_state, Wh, term, pos_list, meta, out, hb);
    for (int k = 1; k < NB - 1; k++) {
        int rows_max = T_LEN / (k + 1);     // S_k <= T/(k+1)
        int gy = (rows_max + 63) / 64;
        pass_gemm<<<dim3(16, gy), dim3(256), 0, stream>>>(gi, bhn, WhT, hb, out, hb, pos_list, meta, k);
    }
    tail_kernel<<<dim3(1), dim3(256), 0, stream>>>(gi, bhn, Wh, pos_list, meta, out);
}

// Round 5
// 435.994 us; speedup vs baseline: 6.4961x; 1.0251x over previous
//
#include <hip/hip_runtime.h>
#include <stdint.h>

#define T_LEN 8192
#define DIN   1024
#define HD    1024
#define TH    3072
#define NB    16      // buckets: 0..14 exact local_step, 15 = clamp (handled by tail_kernel)

typedef __attribute__((ext_vector_type(8))) short bf16x8;
typedef __attribute__((ext_vector_type(4))) float f32x4;

__device__ __forceinline__ unsigned short f2bf(float x) {
    union { float f; unsigned u; } v; v.f = x;
    unsigned r = v.u + 0x7FFFu + ((v.u >> 16) & 1u);
    return (unsigned short)(r >> 16);
}

// async global->LDS, 16B per lane. LDS dest must be wave-uniform base + lane*16;
// global address may be per-lane arbitrary (gather OK).
__device__ __forceinline__ void gld16(const void* g, void* l) {
    __builtin_amdgcn_global_load_lds(
        (const __attribute__((address_space(1))) unsigned int*)(uintptr_t)g,
        (__attribute__((address_space(3))) unsigned int*)(uintptr_t)l,
        16, 0, 0);
}

__device__ __forceinline__ float sigm(float x) { return 1.f / (1.f + __expf(-x)); }
__device__ __forceinline__ float tanh_fast(float x) { return 1.f - 2.f / (1.f + __expf(2.f * x)); }

// ---------------- cast X -> bf16 (r3 lesson: keep casts OFF the GEMM critical path) ----
__global__ void cast_x(const float* __restrict__ X, unsigned short* __restrict__ Xb) {
    int idx = (blockIdx.x * 256 + threadIdx.x) * 4;
    float4 v = *(const float4*)(X + idx);
    ushort4 o; o.x = f2bf(v.x); o.y = f2bf(v.y); o.z = f2bf(v.z); o.w = f2bf(v.w);
    *(ushort4*)(Xb + idx) = o;
}

// ---------------- transpose+cast Wi/Wh [K][3072] -> [3072][K] bf16 ----------------
__global__ void transpose_cast(const float* __restrict__ Wi, const float* __restrict__ Wh,
                               unsigned short* __restrict__ WiT, unsigned short* __restrict__ WhT) {
    const float* src = blockIdx.z ? Wh : Wi;
    unsigned short* dst = blockIdx.z ? WhT : WiT;
    int n0 = blockIdx.x * 64, k0 = blockIdx.y * 64;
    __shared__ unsigned short tile[64][65];
    int tid = threadIdx.x;
    for (int p = 0; p < 16; p++) {
        int idx = tid + p * 256;
        int kl = idx >> 6, nl = idx & 63;
        tile[kl][nl] = f2bf(src[(size_t)(k0 + kl) * TH + n0 + nl]);
    }
    __syncthreads();
    for (int p = 0; p < 16; p++) {
        int idx = tid + p * 256;
        int nl = idx >> 6, kl = idx & 63;
        dst[(size_t)(n0 + nl) * 1024 + k0 + kl] = tile[kl][nl];
    }
}

// ---------------- segment metadata (1 block, 1024 threads) ----------------
// meta[0..NB): counts ; meta[NB..2NB): offsets ; meta[2NB]: last_state nonzero flag
__global__ void meta_kernel(const int* __restrict__ term, const float* __restrict__ last_state,
                            int* __restrict__ pos_list, int* __restrict__ meta) {
    __shared__ int part[1024];
    __shared__ int cnt[NB];
    __shared__ int cur[NB];
    __shared__ int flag;
    int tid = threadIdx.x;
    if (tid < NB) cnt[tid] = 0;
    if (tid == 0) flag = 0;
    __syncthreads();
    int base = tid * 8;
    int mx = -1;
    for (int u = 0; u < 8; u++) {
        int t = base + u;
        int s = (t == 0 || term[t] != 0) ? t : -1;
        mx = s > mx ? s : mx;
    }
    part[tid] = mx;
    __syncthreads();
    for (int d = 1; d < 1024; d <<= 1) {
        int a = part[tid];
        int b = (tid >= d) ? part[tid - d] : -1;
        __syncthreads();
        part[tid] = a > b ? a : b;
        __syncthreads();
    }
    int run = (tid > 0) ? part[tid - 1] : -1;
    int kk[8];
    for (int u = 0; u < 8; u++) {
        int t = base + u;
        int s = (t == 0 || term[t] != 0) ? t : -1;
        run = s > run ? s : run;
        int ls = t - run;
        int k = ls < NB ? ls : NB - 1;
        kk[u] = k;
        atomicAdd(&cnt[k], 1);
    }
    if (last_state[tid] != 0.0f) atomicOr(&flag, 1);
    __syncthreads();
    if (tid == 0) {
        int off = 0;
        for (int k = 0; k < NB; k++) {
            meta[k] = cnt[k];
            meta[NB + k] = off;
            cur[k] = off;
            off += cnt[k];
        }
        meta[2 * NB] = flag;
    }
    __syncthreads();
    for (int u = 0; u < 8; u++) {
        int idx = atomicAdd(&cur[kk[u]], 1);
        pos_list[idx] = base + u;
    }
}

// ---------------- gi = Xb @ WiT^T + bi  (round-1 form: 77.6 us, MfmaUtil 27%) ----------
__global__ __launch_bounds__(256) void gemm_gi(const unsigned short* __restrict__ Xb,
                                               const unsigned short* __restrict__ WiT,
                                               const float* __restrict__ bi,
                                               float* __restrict__ gi) {
    __shared__ unsigned short As[128 * 32];
    __shared__ unsigned short Bs[128 * 32];
    int tid = threadIdx.x;
    int m0 = blockIdx.y * 128, n0 = blockIdx.x * 128;
    int lane = tid & 63, wave = tid >> 6;
    int wm = wave & 1, wn = wave >> 1;
    int quad = lane >> 4, l16 = lane & 15;
    f32x4 acc[4][4] = {};   // 16 f32x4 = promotion ceiling; do NOT enlarge (r2: 24 -> scratch spill)
    for (int kb = 0; kb < 32; kb++) {
        int k0 = kb * 32;
        for (int p = 0; p < 2; p++) {
            int c = tid + p * 256;
            int row = c >> 2, cb = c & 3;
            gld16(Xb + (size_t)(m0 + row) * 1024 + k0 + cb * 8, As + c * 8);
            gld16(WiT + (size_t)(n0 + row) * 1024 + k0 + cb * 8, Bs + c * 8);
        }
        __syncthreads();
        bf16x8 af[4], bfr[4];
        for (int i = 0; i < 4; i++)
            af[i] = *(const bf16x8*)(As + (wm * 64 + i * 16 + l16) * 32 + quad * 8);
        for (int j = 0; j < 4; j++)
            bfr[j] = *(const bf16x8*)(Bs + (wn * 64 + j * 16 + l16) * 32 + quad * 8);
        for (int i = 0; i < 4; i++)
            for (int j = 0; j < 4; j++)
                acc[i][j] = __builtin_amdgcn_mfma_f32_16x16x32_bf16(af[i], bfr[j], acc[i][j], 0, 0, 0);
        __syncthreads();
    }
    for (int j = 0; j < 4; j++) {
        int col = n0 + wn * 64 + j * 16 + l16;
        float bv = bi[col];
        for (int i = 0; i < 4; i++) {
            int rbase = m0 + wm * 64 + i * 16 + quad * 4;
            for (int r = 0; r < 4; r++)
                gi[(size_t)(rbase + r) * TH + col] = acc[i][j][r] + bv;
        }
    }
}

// ---------------- pass 0: segment starts, h_prev == 0 (or last_state for t==0) ----------
__global__ void pass0_kernel(const float* __restrict__ gi, const float* __restrict__ bhn,
                             const float* __restrict__ last_state, const float* __restrict__ Wh,
                             const int* __restrict__ term, const int* __restrict__ pos_list,
                             const int* __restrict__ meta, float* __restrict__ out,
                             unsigned short* __restrict__ hb) {
    int S0 = meta[0];
    int b = blockIdx.x;
    if (b >= S0) return;
    int t = pos_list[meta[NB] + b];
    int tid = threadIdx.x;
    bool ls_path = (t == 0) && (term[0] == 0) && (meta[2 * NB] != 0);
    for (int u = 0; u < 4; u++) {
        int j = tid + u * 256;
        float gr = gi[(size_t)t * TH + j];
        float gz = gi[(size_t)t * TH + 1024 + j];
        float gn = gi[(size_t)t * TH + 2048 + j];
        float hp = 0.f, ghr = 0.f, ghz = 0.f, ghn = 0.f;
        if (ls_path) {  // general fallback (last_state != 0); not taken for this dataset
            hp = last_state[j];
            for (int k = 0; k < 1024; k++) {
                float hk = last_state[k];
                const float* w = Wh + (size_t)k * TH;
                ghr += hk * w[j]; ghz += hk * w[1024 + j]; ghn += hk * w[2048 + j];
            }
        }
        float r = sigm(gr + ghr);
        float z = sigm(gz + ghz);
        float n = tanh_fast(gn + r * (ghn + bhn[j]));
        float h = (1.f - z) * n + z * hp;
        out[(size_t)t * HD + j] = h;
        out[(size_t)(T_LEN + t) * HD + j] = h;
        hb[(size_t)t * HD + j] = f2bf(h);
    }
}

// ---------------- pass k in [1,14]: gathered-row GEMM h_prev @ Wh + fused gates --------
// Tile: 64 gathered rows x 64 h-cols x 3 gates. BK=128 per outer iteration, staged as
// FOUR 32-K sub-tiles (each 64 B-row conflict-free layout) -> 8 iterations (r4 had 16;
// the per-iteration LDS-fill round trip is the latency floor for small passes).
// LDS = 16 KB (A) + 48 KB (B) = 64 KB -> 2 blocks/CU; k=1's ~512 active blocks fit in
// one scheduling wave. ALL staging async gld16 (A gathered from bf16 hb).
// Register budget: acc[2][6]=12 f32x4 — promotion-safe (r2: >16 vectors spills).
__global__ __launch_bounds__(256) void pass_gemm(const float* __restrict__ gi,
                                                 const float* __restrict__ bhn,
                                                 const unsigned short* __restrict__ WhT,
                                                 const unsigned short* __restrict__ hb,
                                                 float* __restrict__ out,
                                                 unsigned short* __restrict__ hbw,
                                                 const int* __restrict__ pos_list,
                                                 const int* __restrict__ meta, int k) {
    int S = meta[k];
    int r0 = blockIdx.y * 64;
    if (r0 >= S) return;
    int off = meta[NB + k];
    int j0 = blockIdx.x * 64;
    __shared__ unsigned short As[4 * 64 * 32];    // 16 KB (four 32-K sub-tiles)
    __shared__ unsigned short Bs[4 * 192 * 32];   // 48 KB (row: gate g*64 + jj)
    int tid = threadIdx.x;
    int lane = tid & 63, wave = tid >> 6;
    int wm = wave & 1, wn = wave >> 1;
    int quad = lane >> 4, l16 = lane & 15;

    // A gather: 256 chunks per sub-tile; chunk id = tid; row=tid>>2, sub=tid&3.
    int arow = tid >> 2, sub = tid & 3;
    bool av = (r0 + arow) < S;
    int t_a = av ? pos_list[off + r0 + arow] : 1;
    const unsigned short* hsrc = hb + (size_t)(t_a - 1) * HD + sub * 8;

    f32x4 acc[2][6] = {};
    for (int kb = 0; kb < 8; kb++) {
        int k0 = kb * 128;
        for (int ks = 0; ks < 4; ks++) {
            int kk0 = k0 + ks * 32;
            for (int p = 0; p < 3; p++) {      // B sub-tile: 768 chunks
                int c = tid + p * 256;
                int row = c >> 2, q = c & 3;
                int g = row >> 6, jj = row & 63;
                gld16(WhT + (size_t)(g * 1024 + j0 + jj) * 1024 + kk0 + q * 8,
                      Bs + ks * 6144 + c * 8);
            }
            // A sub-tile: 256 chunks (gathered rows; garbage rows >= S harmless)
            gld16(hsrc + kk0, As + ks * 2048 + tid * 8);
        }
        __syncthreads();
        for (int ks = 0; ks < 4; ks++) {
            bf16x8 af[2];
            for (int i = 0; i < 2; i++)
                af[i] = *(const bf16x8*)(As + ks * 2048 + (wm * 32 + i * 16 + l16) * 32 + quad * 8);
            for (int n = 0; n < 6; n++) {
                int g = n >> 1, jh = n & 1;
                bf16x8 bv = *(const bf16x8*)(Bs + ks * 6144 + (g * 64 + wn * 32 + jh * 16 + l16) * 32 + quad * 8);
                for (int i = 0; i < 2; i++)
                    acc[i][n] = __builtin_amdgcn_mfma_f32_16x16x32_bf16(af[i], bv, acc[i][n], 0, 0, 0);
            }
        }
        __syncthreads();
    }
    // epilogue: rows r0 + wm*32 + i*16 + quad*4 + r ; cols j0 + wn*32 + jh*16 + l16
    for (int i = 0; i < 2; i++) {
        for (int r = 0; r < 4; r++) {
            int rr = r0 + wm * 32 + i * 16 + quad * 4 + r;
            if (rr >= S) continue;
            int t = pos_list[off + rr];
            const float* girow = gi + (size_t)t * TH;
            const float* hprow = out + (size_t)(t - 1) * HD;
            float* o1 = out + (size_t)t * HD;
            float* o2 = out + (size_t)(T_LEN + t) * HD;
            unsigned short* hbrow = hbw + (size_t)t * HD;
            for (int jh = 0; jh < 2; jh++) {
                int j = j0 + wn * 32 + jh * 16 + l16;
                float ghr = acc[i][0 + jh][r];
                float ghz = acc[i][2 + jh][r];
                float ghn = acc[i][4 + jh][r];
                float rg = sigm(girow[j] + ghr);
                float zg = sigm(girow[1024 + j] + ghz);
                float ng = tanh_fast(girow[2048 + j] + rg * (ghn + bhn[j]));
                float h = (1.f - zg) * ng + zg * hprow[j];
                o1[j] = h;
                o2[j] = h;
                hbrow[j] = f2bf(h);
            }
        }
    }
}

// ---------------- tail: positions with local_step >= NB-1, sequential per time order ----
// Expected S==0 for Bernoulli(1/2) terminations; correctness path for any input.
__global__ void tail_kernel(const float* __restrict__ gi, const float* __restrict__ bhn,
                            const float* __restrict__ Wh,
                            const int* __restrict__ pos_list, const int* __restrict__ meta,
                            float* __restrict__ out) {
    __shared__ int pos[T_LEN];
    int S = meta[NB - 1];
    if (S == 0) return;
    int off = meta[NB + NB - 1];
    int tid = threadIdx.x;
    for (int i = tid; i < S; i += 256) pos[i] = pos_list[off + i];
    __syncthreads();
    if (tid == 0) {   // insertion sort by t (S expected tiny)
        for (int i = 1; i < S; i++) {
            int v = pos[i], j = i - 1;
            while (j >= 0 && pos[j] > v) { pos[j + 1] = pos[j]; j--; }
            pos[j + 1] = v;
        }
    }
    __syncthreads();
    for (int s = 0; s < S; s++) {
        int t = pos[s];
        const float* hp = out + (size_t)(t - 1) * HD;
        const float* girow = gi + (size_t)t * TH;
        float hv[4];
        for (int c = 0; c < 4; c++) {
            int j = tid * 4 + c;
            float ghr = 0.f, ghz = 0.f, ghn = 0.f;
            for (int kk = 0; kk < 1024; kk++) {
                float hk = hp[kk];
                const float* w = Wh + (size_t)kk * TH;
                ghr += hk * w[j]; ghz += hk * w[1024 + j]; ghn += hk * w[2048 + j];
            }
            float rg = sigm(girow[j] + ghr);
            float zg = sigm(girow[1024 + j] + ghz);
            float ng = tanh_fast(girow[2048 + j] + rg * (ghn + bhn[j]));
            hv[c] = (1.f - zg) * ng + zg * hp[j];
        }
        __syncthreads();   // all reads of h_{t-1} complete before writing h_t
        for (int c = 0; c < 4; c++) {
            int j = tid * 4 + c;
            out[(size_t)t * HD + j] = hv[c];
            out[(size_t)(T_LEN + t) * HD + j] = hv[c];
        }
        __syncthreads();
    }
}

extern "C" void kernel_launch(void* const* d_in, const int* in_sizes, int n_in,
                              void* d_out, int out_size, void* d_ws, size_t ws_size,
                              hipStream_t stream) {
    const float* X          = (const float*)d_in[0];
    const int*   term       = (const int*)d_in[1];
    const float* last_state = (const float*)d_in[2];
    const float* Wi         = (const float*)d_in[3];
    const float* bi         = (const float*)d_in[4];
    const float* Wh         = (const float*)d_in[5];
    const float* bhn        = (const float*)d_in[6];
    float* out = (float*)d_out;

    char* ws = (char*)d_ws;
    float*          gi       = (float*)ws;                         // 100,663,296 B
    unsigned short* Xb       = (unsigned short*)(ws + 100663296);  // 16,777,216 B (reused as hb)
    unsigned short* hb       = Xb;  // Xb dead after gemm_gi; stream order guarantees safety
    unsigned short* WiT      = (unsigned short*)(ws + 117440512);  //  6,291,456 B
    unsigned short* WhT      = (unsigned short*)(ws + 123731968);  //  6,291,456 B
    int*            pos_list = (int*)(ws + 130023424);             //     32,768 B
    int*            meta     = (int*)(ws + 130056192);             //        512 B

    cast_x<<<dim3(8192), dim3(256), 0, stream>>>(X, Xb);
    transpose_cast<<<dim3(48, 16, 2), dim3(256), 0, stream>>>(Wi, Wh, WiT, WhT);
    meta_kernel<<<dim3(1), dim3(1024), 0, stream>>>(term, last_state, pos_list, meta);
    gemm_gi<<<dim3(24, 64), dim3(256), 0, stream>>>(Xb, WiT, bi, gi);
    pass0_kernel<<<dim3(8192), dim3(256), 0, stream>>>(gi, bhn, last_state, Wh, term, pos_list, meta, out, hb);
    for (int k = 1; k < NB - 1; k++) {
        int rows_max = T_LEN / (k + 1);     // S_k <= T/(k+1)
        int gy = (rows_max + 63) / 64;
        pass_gemm<<<dim3(16, gy), dim3(256), 0, stream>>>(gi, bhn, WhT, hb, out, hb, pos_list, meta, k);
    }
    tail_kernel<<<dim3(1), dim3(256), 0, stream>>>(gi, bhn, Wh, pos_list, meta, out);
}